// Round 2
// baseline (789.655 us; speedup 1.0000x reference)
//
#include <hip/hip_runtime.h>
#include <hip/hip_bf16.h>
#include <math.h>

#define NHEADS 12
#define HEAD   64
#define DM     768
#define NB     256
#define SLEN   1024
#define NBATCH 8

// Flag semantics: 1 = inputs are bf16, 0 = inputs are fp32.
__device__ __forceinline__ float gload(const void* p, long i, int bf) {
  return bf ? __bfloat162float(((const __hip_bfloat16*)p)[i])
            : ((const float*)p)[i];
}

// ---------------------------------------------------------------------------
// Detect input dtype. If the buffer holds bf16 N(0,1) data, max|bf16| ~ 4.
// If it holds fp32 data, the interleaved low-mantissa halves read as bf16 have
// uniform-random exponents -> max is astronomically large (w.p. 1 - 1e-60).
// ---------------------------------------------------------------------------
__global__ void detect_dtype(const void* x, int* flag) {
  __shared__ float red[256];
  int t = threadIdx.x;
  const __hip_bfloat16* p = (const __hip_bfloat16*)x;
  float a = fabsf(__bfloat162float(p[t * 2]));
  float b = fabsf(__bfloat162float(p[t * 2 + 1]));
  float m = fmaxf(a, b);
  red[t] = m;
  __syncthreads();
  for (int s = 128; s > 0; s >>= 1) {
    if (t < s) red[t] = fmaxf(red[t], red[t + s]);
    __syncthreads();
  }
  if (t == 0) flag[0] = (red[0] < 1e4f) ? 1 : 0;
}

// Convert any input tensor to a canonical fp32 workspace copy.
__global__ void convertk(const void* __restrict__ src, float* __restrict__ dst,
                         int n, const int* __restrict__ flagp) {
  int bf = flagp[0];
  int i = blockIdx.x * 256 + threadIdx.x;
  if (i < n) dst[i] = gload(src, i, bf);
}

// ---------------------------------------------------------------------------
// Bmat[m, n] = sum_k G[k,m] * X[k,n];  G fp32 [1024,256], X = x (flagged dtype)
// viewed [1024, 6144]. C fp32 row-major [256, 6144]. Tile 64x64, K-tile 16.
// ---------------------------------------------------------------------------
__global__ __launch_bounds__(256) void gemm_bmat(
    const float* __restrict__ G, const void* __restrict__ X,
    float* __restrict__ C, const int* __restrict__ flagp) {
  int bf = flagp[0];
  __shared__ float As[16][64];
  __shared__ float Bs[16][65];
  const int m0 = blockIdx.y * 64;
  const int n0 = blockIdx.x * 64;
  const int tid = threadIdx.x;
  const int tx = tid & 15, ty = tid >> 4;
  float acc[4][4] = {};
  for (int k0 = 0; k0 < 1024; k0 += 16) {
#pragma unroll
    for (int i = 0; i < 4; i++) {
      int idx = tid + i * 256;
      int kk = idx >> 6, mm = idx & 63;
      As[kk][mm] = G[(long)(k0 + kk) * 256 + m0 + mm];
      Bs[kk][mm] = gload(X, (long)(k0 + kk) * 6144 + n0 + mm, bf);
    }
    __syncthreads();
#pragma unroll
    for (int kk = 0; kk < 16; kk++) {
      float a[4], b[4];
#pragma unroll
      for (int i = 0; i < 4; i++) a[i] = As[kk][ty * 4 + i];
#pragma unroll
      for (int j = 0; j < 4; j++) b[j] = Bs[kk][tx * 4 + j];
#pragma unroll
      for (int i = 0; i < 4; i++)
#pragma unroll
        for (int j = 0; j < 4; j++) acc[i][j] += a[i] * b[j];
    }
    __syncthreads();
  }
#pragma unroll
  for (int i = 0; i < 4; i++)
#pragma unroll
    for (int j = 0; j < 4; j++)
      C[(long)(m0 + ty * 4 + i) * 6144 + (n0 + tx * 4 + j)] = acc[i][j];
}

// ---------------------------------------------------------------------------
// NT GEMM: C(z)[m,n] = sum_k A(z)[m,k] * W[n,k].  A fp32, W fp32.
// Output offset: z*c_batch + m*om + (n>>6)*oh + (n&63).
// Store fp32, or bf16 when (use_flag && *flagp).
// ---------------------------------------------------------------------------
__global__ __launch_bounds__(256) void gemm_nt(
    const float* __restrict__ A, const float* __restrict__ W,
    void* __restrict__ C, long a_batch, int lda, long c_batch, int om, int oh,
    const int* __restrict__ flagp, int use_flag) {
  int bf = use_flag ? flagp[0] : 0;
  __shared__ float As[64][17];
  __shared__ float Ws[64][17];
  const int z = blockIdx.z;
  const int m0 = blockIdx.y * 64;
  const int n0 = blockIdx.x * 64;
  const float* Ab = A + (long)z * a_batch;
  const int tid = threadIdx.x;
  const int tx = tid & 15, ty = tid >> 4;
  const int mm = tid >> 2;
  const int kb = (tid & 3) * 4;
  float acc[4][4] = {};
  for (int k0 = 0; k0 < 768; k0 += 16) {
#pragma unroll
    for (int i = 0; i < 4; i++) {
      As[mm][kb + i] = Ab[(long)(m0 + mm) * lda + k0 + kb + i];
      Ws[mm][kb + i] = W[(long)(n0 + mm) * 768 + k0 + kb + i];
    }
    __syncthreads();
#pragma unroll
    for (int kk = 0; kk < 16; kk++) {
      float a[4], b[4];
#pragma unroll
      for (int i = 0; i < 4; i++) a[i] = As[ty * 4 + i][kk];
#pragma unroll
      for (int j = 0; j < 4; j++) b[j] = Ws[tx * 4 + j][kk];
#pragma unroll
      for (int i = 0; i < 4; i++)
#pragma unroll
        for (int j = 0; j < 4; j++) acc[i][j] += a[i] * b[j];
    }
    __syncthreads();
  }
#pragma unroll
  for (int i = 0; i < 4; i++) {
    int m = m0 + ty * 4 + i;
#pragma unroll
    for (int j = 0; j < 4; j++) {
      int n = n0 + tx * 4 + j;
      long off = (long)z * c_batch + (long)m * om + (long)(n >> 6) * oh + (n & 63);
      if (bf) ((__hip_bfloat16*)C)[off] = __float2bfloat16(acc[i][j]);
      else    ((float*)C)[off] = acc[i][j];
    }
  }
}

// ---------------------------------------------------------------------------
// bmu[b,d] = sum_n w_mu[n] * Bmat[n, b*768+d]   (and bsig with w_sigma)
// 12288 threads: t -> (which, b*768+d)
// ---------------------------------------------------------------------------
__global__ __launch_bounds__(256) void bvec(
    const float* __restrict__ Bmat, const float* __restrict__ wmuf,
    const float* __restrict__ wsigf, float* __restrict__ bmu,
    float* __restrict__ bsig) {
  int t = blockIdx.x * 256 + threadIdx.x;
  int w = t / 6144, r = t % 6144;
  const float* wv = w ? wsigf : wmuf;
  float acc = 0.f;
  for (int n = 0; n < NB; n++) acc += wv[n] * Bmat[(long)n * 6144 + r];
  (w ? bsig : bmu)[r] = acc;
}

// kmu[b,c] = sum_d bmu[b,d] * Wk[c,d]   (c = h*64+dh), and ksig with bsig.
__global__ __launch_bounds__(256) void kvec(
    const float* __restrict__ Wkf, const float* __restrict__ bmu,
    const float* __restrict__ bsig, float* __restrict__ kmu,
    float* __restrict__ ksig) {
  int t = blockIdx.x * 256 + threadIdx.x;
  int w = t / 6144, r = t % 6144;
  int b = r / 768, c = r % 768;
  const float* bv = (w ? bsig : bmu) + b * 768;
  const float* wk = Wkf + (long)c * 768;
  float acc = 0.f;
  for (int d = 0; d < 768; d++) acc += bv[d] * wk[d];
  (w ? ksig : kmu)[r] = acc;
}

// wqm[b,h,d] = sum_dh Wq[h*64+dh, d] * kmu[b, h*64+dh]   (and wqs with ksig)
__global__ __launch_bounds__(256) void wqvec(
    const float* __restrict__ Wqf, const float* __restrict__ kmu,
    const float* __restrict__ ksig, float* __restrict__ wqm,
    float* __restrict__ wqs) {
  int t = blockIdx.x * 256 + threadIdx.x;
  int w = t / 73728, r = t % 73728;
  int b = r / 9216, h = (r % 9216) / 768, d = r % 768;
  const float* kv = (w ? ksig : kmu) + b * 768 + h * 64;
  float acc = 0.f;
  for (int dh = 0; dh < 64; dh++)
    acc += Wqf[(long)(h * 64 + dh) * 768 + d] * kv[dh];
  (w ? wqs : wqm)[r] = acc;
}

// ---------------------------------------------------------------------------
// amu[b, hh, qrow] = dot768(q[qrow, b, :], wq{m|s}[b, hh, :]); one wave/q-row.
// hh in [0,12) -> mu path, [12,24) -> sigma path.
// ---------------------------------------------------------------------------
__global__ __launch_bounds__(256) void amu_kernel(
    const void* __restrict__ q, const float* __restrict__ wqm,
    const float* __restrict__ wqs, float* __restrict__ amu,
    const int* __restrict__ flagp) {
  int bf = flagp[0];
  int lane = threadIdx.x & 63;
  int wave = threadIdx.x >> 6;
  int qrow = blockIdx.x * 4 + wave;
  int b = blockIdx.y;
  float qv[12];
  long base = ((long)qrow * 8 + b) * 768 + lane;
#pragma unroll
  for (int j = 0; j < 12; j++) qv[j] = gload(q, base + 64 * j, bf);
  for (int hh = 0; hh < 24; hh++) {
    const float* vec = (hh < 12) ? (wqm + ((long)b * 12 + hh) * 768)
                                 : (wqs + ((long)b * 12 + hh - 12) * 768);
    float p = 0.f;
#pragma unroll
    for (int j = 0; j < 12; j++) p += qv[j] * vec[lane + 64 * j];
#pragma unroll
    for (int m = 32; m >= 1; m >>= 1) p += __shfl_xor(p, m);
    if (lane == 0) amu[((long)b * 24 + hh) * 1024 + qrow] = p;
  }
}

// ---------------------------------------------------------------------------
// Fused attention: mu/sigma -> Gaussian basis expectations r -> r . values.
// ---------------------------------------------------------------------------
__global__ __launch_bounds__(256) void attn(
    const float* __restrict__ values, const float* __restrict__ amu,
    const float* __restrict__ mubf, const float* __restrict__ sigbf,
    float* __restrict__ context) {
  const int b = blockIdx.x, h = blockIdx.y, qc = blockIdx.z;
  const int tid = threadIdx.x;
  const int qrow = qc * 256 + tid;
  __shared__ float s_mub[NB], s_sb2[NB];
  {
    float sb = sigbf[tid];
    s_mub[tid] = mubf[tid];
    s_sb2[tid] = sb * sb;
  }
  __syncthreads();
  float araw = amu[((long)b * 24 + h) * 1024 + qrow] * 0.125f;
  float sraw = amu[((long)b * 24 + 12 + h) * 1024 + qrow] * 0.125f;
  float mu = 1.f / (1.f + expf(-araw));
  float sig = fmaxf(sraw, 0.f) + log1pf(expf(-fabsf(sraw)));  // softplus
  float ctx[HEAD];
#pragma unroll
  for (int d = 0; d < HEAD; d++) ctx[d] = 0.f;
  const float* vp = values + ((long)(b * NHEADS + h)) * NB * HEAD;
  for (int n = 0; n < NB; n++) {
    float inv_s = rsqrtf(s_sb2[n] + sig);
    float t = (mu - s_mub[n]) * inv_s;
    float r = 0.3989422804014327f * inv_s * expf(-0.5f * t * t);
    const float* vrow = vp + n * HEAD;
#pragma unroll
    for (int d = 0; d < HEAD; d++) ctx[d] += r * vrow[d];
  }
  float* cp = context + ((long)(b * SLEN + qrow)) * DM + h * HEAD;
#pragma unroll
  for (int d = 0; d < HEAD; d++) cp[d] = ctx[d];
}

// ---------------------------------------------------------------------------
extern "C" void kernel_launch(void* const* d_in, const int* in_sizes, int n_in,
                              void* d_out, int out_size, void* d_ws, size_t ws_size,
                              hipStream_t stream) {
  const void* x    = d_in[0];
  const void* q    = d_in[1];
  const void* Wq   = d_in[2];
  const void* Wk   = d_in[3];
  const void* Wv   = d_in[4];
  const void* Wo   = d_in[5];
  const void* wmu  = d_in[6];
  const void* wsig = d_in[7];
  const void* mub  = d_in[8];
  const void* sigb = d_in[9];
  const void* G    = d_in[10];

  int* flagp = (int*)d_ws;
  float* base = (float*)d_ws + 16;
  float* Wqf   = base;              // 589824
  float* Wkf   = Wqf + 589824;      // 589824
  float* Wvf   = Wkf + 589824;      // 589824
  float* Wof   = Wvf + 589824;      // 589824
  float* wmuf  = Wof + 589824;      // 256
  float* wsigf = wmuf + 256;        // 256
  float* mubf  = wsigf + 256;       // 256
  float* sigbf = mubf + 256;        // 256
  float* Gf    = sigbf + 256;       // 262144
  float* Bmat  = Gf + 262144;       // 1572864  [256, 6144]
  float* values= Bmat + 1572864;    // 1572864  [B,H,256,64]
  float* bmu   = values + 1572864;  // 6144
  float* bsig  = bmu + 6144;        // 6144
  float* kmu   = bsig + 6144;       // 6144
  float* ksig  = kmu + 6144;        // 6144
  float* wqm   = ksig + 6144;       // 73728
  float* wqs   = wqm + 73728;       // 73728
  float* amu   = wqs + 73728;       // 196608  [B,24,1024]
  float* ctx   = amu + 196608;      // 6291456 [B,1024,768]
  // total ~12.43M floats = 49.7 MB

  detect_dtype<<<1, 256, 0, stream>>>(x, flagp);

  convertk<<<2304, 256, 0, stream>>>(Wq, Wqf, 589824, flagp);
  convertk<<<2304, 256, 0, stream>>>(Wk, Wkf, 589824, flagp);
  convertk<<<2304, 256, 0, stream>>>(Wv, Wvf, 589824, flagp);
  convertk<<<2304, 256, 0, stream>>>(Wo, Wof, 589824, flagp);
  convertk<<<1, 256, 0, stream>>>(wmu, wmuf, 256, flagp);
  convertk<<<1, 256, 0, stream>>>(wsig, wsigf, 256, flagp);
  convertk<<<1, 256, 0, stream>>>(mub, mubf, 256, flagp);
  convertk<<<1, 256, 0, stream>>>(sigb, sigbf, 256, flagp);
  convertk<<<1024, 256, 0, stream>>>(G, Gf, 262144, flagp);

  // Bmat = G^T @ x
  gemm_bmat<<<dim3(96, 4, 1), 256, 0, stream>>>(Gf, x, Bmat, flagp);

  // values(z) = Bmat_z @ Wv^T -> [B,H,256,64]
  gemm_nt<<<dim3(12, 4, 8), 256, 0, stream>>>(
      Bmat, Wvf, values, /*a_batch=*/768, /*lda=*/6144,
      /*c_batch=*/196608, /*om=*/64, /*oh=*/16384, flagp, 0);

  // scores@w collapse chain: bmu/bsig -> kmu/ksig -> wqm/wqs -> amu
  bvec<<<48, 256, 0, stream>>>(Bmat, wmuf, wsigf, bmu, bsig);
  kvec<<<48, 256, 0, stream>>>(Wkf, bmu, bsig, kmu, ksig);
  wqvec<<<576, 256, 0, stream>>>(Wqf, kmu, ksig, wqm, wqs);
  amu_kernel<<<dim3(256, 8), 256, 0, stream>>>(q, wqm, wqs, amu, flagp);

  // fused attention -> context [B,1024,768]
  attn<<<dim3(8, 12, 4), 256, 0, stream>>>(values, amu, mubf, sigbf, ctx);

  // out = context @ Wo^T (store dtype per flag)
  gemm_nt<<<dim3(12, 16, 8), 256, 0, stream>>>(
      ctx, Wof, d_out, /*a_batch=*/786432, /*lda=*/768,
      /*c_batch=*/786432, /*om=*/768, /*oh=*/64, flagp, 1);
}